// Round 1
// baseline (1136.551 us; speedup 1.0000x reference)
//
#include <hip/hip_runtime.h>
#include <hip/hip_bf16.h>

#define N_NODES 20000
#define N_EDGES 320000
#define HD 512           // hidden dim == input dim == 512

// ---------------- GEMM: C[n,m] = sum_k A[n,k]*B[k,m], K=M=512 ----------------
__global__ __launch_bounds__(256) void gemm_k(const float* __restrict__ A,
                                              const float* __restrict__ B,
                                              float* __restrict__ C,
                                              int Nrows) {
    __shared__ float As[64][17];   // +1 pad: avoid 4-way bank conflict on ty groups
    __shared__ float Bs[16][64];
    const int tx = threadIdx.x & 15;
    const int ty = threadIdx.x >> 4;
    const int row0 = blockIdx.y * 64;
    const int col0 = blockIdx.x * 64;

    float acc[4][4] = {};

    for (int k0 = 0; k0 < HD; k0 += 16) {
        // load A tile 64x16 (1024 elems, 4/thread)
        #pragma unroll
        for (int l = 0; l < 4; ++l) {
            int idx = threadIdx.x + l * 256;
            int an = idx >> 4, ak = idx & 15;
            int gr = row0 + an;
            As[an][ak] = (gr < Nrows) ? A[(size_t)gr * HD + k0 + ak] : 0.f;
        }
        // load B tile 16x64
        #pragma unroll
        for (int l = 0; l < 4; ++l) {
            int idx = threadIdx.x + l * 256;
            int bk = idx >> 6, bm = idx & 63;
            Bs[bk][bm] = B[(size_t)(k0 + bk) * HD + col0 + bm];
        }
        __syncthreads();
        #pragma unroll
        for (int kk = 0; kk < 16; ++kk) {
            float a[4], b[4];
            #pragma unroll
            for (int i = 0; i < 4; ++i) a[i] = As[ty * 4 + i][kk];
            #pragma unroll
            for (int j = 0; j < 4; ++j) b[j] = Bs[kk][tx * 4 + j];
            #pragma unroll
            for (int i = 0; i < 4; ++i)
                #pragma unroll
                for (int j = 0; j < 4; ++j) acc[i][j] += a[i] * b[j];
        }
        __syncthreads();
    }
    #pragma unroll
    for (int i = 0; i < 4; ++i) {
        int gr = row0 + ty * 4 + i;
        if (gr < Nrows) {
            float4 o = make_float4(acc[i][0], acc[i][1], acc[i][2], acc[i][3]);
            *(float4*)&C[(size_t)gr * HD + col0 + tx * 4] = o;
        }
    }
}

// ---------------- CSR build ----------------
__global__ void hist_k(const int* __restrict__ rows, int* __restrict__ deg) {
    int e = blockIdx.x * blockDim.x + threadIdx.x;
    if (e < N_EDGES) atomicAdd(&deg[rows[e]], 1);
}

__global__ void scan_k(const int* __restrict__ deg, int* __restrict__ rowstart,
                       int* __restrict__ cursor) {
    __shared__ int buf[256];
    const int tid = threadIdx.x;
    int carry = 0;
    for (int base = 0; base < N_NODES; base += 256) {
        int i = base + tid;
        int v = (i < N_NODES) ? deg[i] : 0;
        buf[tid] = v;
        __syncthreads();
        for (int off = 1; off < 256; off <<= 1) {
            int t = (tid >= off) ? buf[tid - off] : 0;
            __syncthreads();
            buf[tid] += t;
            __syncthreads();
        }
        if (i < N_NODES) {
            int ex = carry + buf[tid] - v;   // exclusive
            rowstart[i] = ex;
            cursor[i]   = ex;
        }
        carry += buf[255];
        __syncthreads();
    }
    if (tid == 0) rowstart[N_NODES] = carry;
}

__global__ void fill_k(const int* __restrict__ rows, int* __restrict__ cursor,
                       int* __restrict__ csr_e) {
    int e = blockIdx.x * blockDim.x + threadIdx.x;
    if (e < N_EDGES) {
        int p = atomicAdd(&cursor[rows[e]], 1);
        csr_e[p] = e;
    }
}

// ---------------- aggregate: h[r,:] = relu(sum_e w_e * s[col_e,:] + b) --------
__global__ __launch_bounds__(128) void agg_k(const float* __restrict__ s,
                                             const int* __restrict__ rowstart,
                                             const int* __restrict__ csr_e,
                                             const int* __restrict__ cols,
                                             const float* __restrict__ vals,
                                             const float* __restrict__ bias,
                                             float* __restrict__ hout) {
    const int r = blockIdx.x;
    const int tid = threadIdx.x;
    const float4* s4 = (const float4*)s;
    float4 acc = make_float4(0.f, 0.f, 0.f, 0.f);
    const int beg = rowstart[r], end = rowstart[r + 1];
    for (int j = beg; j < end; ++j) {
        int e = csr_e[j];
        int col = cols[e];          // broadcast across the wave
        float w = vals[e];
        float4 sv = s4[(size_t)col * 128 + tid];
        acc.x += w * sv.x; acc.y += w * sv.y;
        acc.z += w * sv.z; acc.w += w * sv.w;
    }
    float4 b4 = ((const float4*)bias)[tid];
    float4 o;
    o.x = fmaxf(acc.x + b4.x, 0.f);
    o.y = fmaxf(acc.y + b4.y, 0.f);
    o.z = fmaxf(acc.z + b4.z, 0.f);
    o.w = fmaxf(acc.w + b4.w, 0.f);
    ((float4*)hout)[(size_t)r * 128 + tid] = o;
}

// ---------------- pool: per-channel max & sum over N rows ----------------
__global__ __launch_bounds__(256) void pool_k(const float* __restrict__ h,
                                              float* __restrict__ pmax,
                                              float* __restrict__ psum) {
    const int tid = threadIdx.x;
    const int c0 = tid * 2;
    float m0 = 0.f, m1 = 0.f, s0 = 0.f, s1 = 0.f;   // relu output >= 0
    for (int r = blockIdx.x; r < N_NODES; r += gridDim.x) {
        float2 v = ((const float2*)h)[(size_t)r * 256 + tid];
        m0 = fmaxf(m0, v.x); m1 = fmaxf(m1, v.y);
        s0 += v.x;           s1 += v.y;
    }
    // values >= 0: int-bit ordering == float ordering
    atomicMax((int*)&pmax[c0],     __float_as_int(m0));
    atomicMax((int*)&pmax[c0 + 1], __float_as_int(m1));
    atomicAdd(&psum[c0],     s0);
    atomicAdd(&psum[c0 + 1], s1);
}

// ---------------- head MLP + log_softmax ----------------
__global__ __launch_bounds__(256) void mlp_k(const float* __restrict__ pool_max,
                                             const float* __restrict__ pool_sum,
                                             const float* __restrict__ l1W,
                                             const float* __restrict__ l1b,
                                             const float* __restrict__ l2W,
                                             const float* __restrict__ l2b,
                                             const float* __restrict__ l3W,
                                             const float* __restrict__ l3b,
                                             float* __restrict__ out) {
    __shared__ float g[1024];
    __shared__ float a1[128];
    __shared__ float a2[64];
    __shared__ float a3[10];
    const int tid = threadIdx.x;
    for (int c = tid; c < 512; c += 256) {
        g[c]       = pool_max[c] + pool_max[512 + c] + pool_max[1024 + c];
        g[512 + c] = (pool_sum[c] + pool_sum[512 + c] + pool_sum[1024 + c]) *
                     (1.0f / N_NODES);
    }
    __syncthreads();
    if (tid < 128) {
        float acc = l1b[tid];
        for (int k = 0; k < 1024; ++k) acc += g[k] * l1W[k * 128 + tid];
        a1[tid] = fmaxf(acc, 0.f);
    }
    __syncthreads();
    if (tid < 64) {
        float acc = l2b[tid];
        for (int k = 0; k < 128; ++k) acc += a1[k] * l2W[k * 64 + tid];
        a2[tid] = fmaxf(acc, 0.f);
    }
    __syncthreads();
    if (tid < 10) {
        float acc = l3b[tid];
        for (int k = 0; k < 64; ++k) acc += a2[k] * l3W[k * 10 + tid];
        a3[tid] = acc;
    }
    __syncthreads();
    if (tid == 0) {
        float m = a3[0];
        for (int j = 1; j < 10; ++j) m = fmaxf(m, a3[j]);
        float ssum = 0.f;
        for (int j = 0; j < 10; ++j) ssum += expf(a3[j] - m);
        float lse = m + logf(ssum);
        for (int j = 0; j < 10; ++j) out[j] = a3[j] - lse;
    }
}

extern "C" void kernel_launch(void* const* d_in, const int* in_sizes, int n_in,
                              void* d_out, int out_size, void* d_ws, size_t ws_size,
                              hipStream_t stream) {
    const float* x    = (const float*)d_in[0];
    const int*   rows = (const int*)  d_in[1];
    const int*   cols = (const int*)  d_in[2];
    const float* vals = (const float*)d_in[3];
    const float* W1   = (const float*)d_in[4];
    const float* b1   = (const float*)d_in[5];
    const float* W2   = (const float*)d_in[6];
    const float* b2   = (const float*)d_in[7];
    const float* W3   = (const float*)d_in[8];
    const float* b3   = (const float*)d_in[9];
    const float* l1W  = (const float*)d_in[10];
    const float* l1b  = (const float*)d_in[11];
    const float* l2W  = (const float*)d_in[12];
    const float* l2b  = (const float*)d_in[13];
    const float* l3W  = (const float*)d_in[14];
    const float* l3b  = (const float*)d_in[15];
    float* out = (float*)d_out;

    char* ws = (char*)d_ws;
    size_t off = 0;
    auto alloc = [&](size_t bytes) {
        void* p = ws + off;
        off += (bytes + 255) & ~(size_t)255;
        return p;
    };
    float* s        = (float*)alloc((size_t)N_NODES * HD * 4);   // 40.96 MB
    float* hbuf     = (float*)alloc((size_t)N_NODES * HD * 4);   // 40.96 MB
    int*   deg      = (int*)  alloc((size_t)N_NODES * 4);
    int*   rowstart = (int*)  alloc((size_t)(N_NODES + 1) * 4);
    int*   cursor   = (int*)  alloc((size_t)N_NODES * 4);
    int*   csr_e    = (int*)  alloc((size_t)N_EDGES * 4);
    float* pmax     = (float*)alloc((size_t)3 * 512 * 4);
    float* psum     = (float*)alloc((size_t)3 * 512 * 4);
    (void)ws_size; (void)in_sizes; (void)n_in; (void)out_size;

    hipMemsetAsync(deg,  0, (size_t)N_NODES * 4, stream);
    hipMemsetAsync(pmax, 0, (size_t)3 * 512 * 4, stream);
    hipMemsetAsync(psum, 0, (size_t)3 * 512 * 4, stream);

    const int EB = (N_EDGES + 255) / 256;
    hist_k<<<EB, 256, 0, stream>>>(rows, deg);
    scan_k<<<1, 256, 0, stream>>>(deg, rowstart, cursor);
    fill_k<<<EB, 256, 0, stream>>>(rows, cursor, csr_e);

    dim3 ggrid(HD / 64, (N_NODES + 63) / 64);

    // layer 1
    gemm_k<<<ggrid, 256, 0, stream>>>(x, W1, s, N_NODES);
    agg_k<<<N_NODES, 128, 0, stream>>>(s, rowstart, csr_e, cols, vals, b1, hbuf);
    pool_k<<<256, 256, 0, stream>>>(hbuf, pmax, psum);

    // layer 2
    gemm_k<<<ggrid, 256, 0, stream>>>(hbuf, W2, s, N_NODES);
    agg_k<<<N_NODES, 128, 0, stream>>>(s, rowstart, csr_e, cols, vals, b2, hbuf);
    pool_k<<<256, 256, 0, stream>>>(hbuf, pmax + 512, psum + 512);

    // layer 3
    gemm_k<<<ggrid, 256, 0, stream>>>(hbuf, W3, s, N_NODES);
    agg_k<<<N_NODES, 128, 0, stream>>>(s, rowstart, csr_e, cols, vals, b3, hbuf);
    pool_k<<<256, 256, 0, stream>>>(hbuf, pmax + 1024, psum + 1024);

    mlp_k<<<1, 256, 0, stream>>>(pmax, psum, l1W, l1b, l2W, l2b, l3W, l3b, out);
}

// Round 2
// 565.173 us; speedup vs baseline: 2.0110x; 2.0110x over previous
//
#include <hip/hip_runtime.h>
#include <hip/hip_bf16.h>

#define N_NODES 20000
#define N_EDGES 320000
#define HD 512

typedef __attribute__((ext_vector_type(8))) short bf16x8;
typedef __attribute__((ext_vector_type(4))) float f32x4;

// ---------- bf16 helpers (RNE pack, cheap unpack) ----------
__device__ inline ushort f2bf(float f) {
    uint u = __float_as_uint(f);
    uint r = (u + 0x7fffu + ((u >> 16) & 1u)) >> 16;
    return (ushort)r;
}
__device__ inline uint pack2(float a, float b) {
    return (uint)f2bf(a) | ((uint)f2bf(b) << 16);
}
__device__ inline float bflo(uint u) { return __uint_as_float(u << 16); }
__device__ inline float bfhi(uint u) { return __uint_as_float(u & 0xffff0000u); }

// ---------- convert fp32 -> bf16, 8 elems/thread ----------
__global__ __launch_bounds__(256) void cvt_k(const float* __restrict__ in,
                                             ushort* __restrict__ out, int nchunk) {
    int c = blockIdx.x * 256 + threadIdx.x;
    if (c < nchunk) {
        const float4* p = (const float4*)in + (size_t)c * 2;
        float4 a = p[0], b = p[1];
        uint4 o;
        o.x = pack2(a.x, a.y); o.y = pack2(a.z, a.w);
        o.z = pack2(b.x, b.y); o.w = pack2(b.z, b.w);
        ((uint4*)out)[c] = o;
    }
}

// ---------- W [K][N] fp32 -> Wt [N][K] bf16 (LDS tile transpose) ----------
__global__ __launch_bounds__(256) void wt_k(const float* __restrict__ W0,
                                            const float* __restrict__ W1,
                                            const float* __restrict__ W2,
                                            ushort* __restrict__ T0,
                                            ushort* __restrict__ T1,
                                            ushort* __restrict__ T2) {
    const float* W = (blockIdx.z == 0) ? W0 : (blockIdx.z == 1) ? W1 : W2;
    ushort* T      = (blockIdx.z == 0) ? T0 : (blockIdx.z == 1) ? T1 : T2;
    __shared__ float t[64][65];
    int c = threadIdx.x & 63, r4 = threadIdx.x >> 6;
    int kb = blockIdx.x * 64, nb = blockIdx.y * 64;
    #pragma unroll
    for (int l = 0; l < 16; ++l) {
        int r = l * 4 + r4;
        t[r][c] = W[(size_t)(kb + r) * HD + nb + c];
    }
    __syncthreads();
    #pragma unroll
    for (int l = 0; l < 16; ++l) {
        int r = l * 4 + r4;
        T[(size_t)(nb + r) * HD + kb + c] = f2bf(t[c][r]);
    }
}

// ---------- bf16 MFMA GEMM: C[M,512] = A[M,512] * Bt[n][k]^T ----------
#define LDSK 40   // 32 + 8 pad: frag ds_read_b128 -> 8 banks/16 lanes = 2-way = free
__global__ __launch_bounds__(256) void gemm_bf16_k(const ushort* __restrict__ A,
                                                   const ushort* __restrict__ Bt,
                                                   ushort* __restrict__ C, int M) {
    __shared__ __align__(16) short As[128 * LDSK];
    __shared__ __align__(16) short Bs[128 * LDSK];
    const int tid = threadIdx.x;
    const int lane = tid & 63;
    const int wave = tid >> 6;
    const int l15 = lane & 15;
    const int q = lane >> 4;
    const int wrow = wave >> 1, wcol = wave & 1;
    const int row0 = blockIdx.y * 128;
    const int col0 = blockIdx.x * 128;

    f32x4 acc[4][4] = {};

    for (int k0 = 0; k0 < HD; k0 += 32) {
        #pragma unroll
        for (int l = 0; l < 2; ++l) {
            int c = tid + l * 256;          // 512 chunks of 8 bf16
            int row = c >> 2, kc = c & 3;
            uint4 v = make_uint4(0u, 0u, 0u, 0u);
            int gr = row0 + row;
            if (gr < M) v = *(const uint4*)&A[(size_t)gr * HD + k0 + kc * 8];
            *(uint4*)&As[row * LDSK + kc * 8] = v;
            uint4 w = *(const uint4*)&Bt[(size_t)(col0 + row) * HD + k0 + kc * 8];
            *(uint4*)&Bs[row * LDSK + kc * 8] = w;
        }
        __syncthreads();
        bf16x8 aF[4], bF[4];
        #pragma unroll
        for (int i = 0; i < 4; ++i)
            aF[i] = *(bf16x8*)&As[(wrow * 64 + i * 16 + l15) * LDSK + q * 8];
        #pragma unroll
        for (int j = 0; j < 4; ++j)
            bF[j] = *(bf16x8*)&Bs[(wcol * 64 + j * 16 + l15) * LDSK + q * 8];
        #pragma unroll
        for (int i = 0; i < 4; ++i)
            #pragma unroll
            for (int j = 0; j < 4; ++j)
                acc[i][j] = __builtin_amdgcn_mfma_f32_16x16x32_bf16(aF[i], bF[j], acc[i][j], 0, 0, 0);
        __syncthreads();
    }
    #pragma unroll
    for (int i = 0; i < 4; ++i) {
        #pragma unroll
        for (int r = 0; r < 4; ++r) {
            int gr = row0 + wrow * 64 + i * 16 + q * 4 + r;
            if (gr < M) {
                #pragma unroll
                for (int j = 0; j < 4; ++j) {
                    int gc = col0 + wcol * 64 + j * 16 + l15;
                    C[(size_t)gr * HD + gc] = f2bf(acc[i][j][r]);
                }
            }
        }
    }
}

// ---------- CSR build ----------
__global__ void hist_k(const int* __restrict__ rows, int* __restrict__ deg) {
    int e = blockIdx.x * blockDim.x + threadIdx.x;
    if (e < N_EDGES) atomicAdd(&deg[rows[e]], 1);
}

__global__ void scan_k(const int* __restrict__ deg, int* __restrict__ rowstart,
                       int* __restrict__ cursor) {
    __shared__ int buf[256];
    const int tid = threadIdx.x;
    int carry = 0;
    for (int base = 0; base < N_NODES; base += 256) {
        int i = base + tid;
        int v = (i < N_NODES) ? deg[i] : 0;
        buf[tid] = v;
        __syncthreads();
        for (int off = 1; off < 256; off <<= 1) {
            int t = (tid >= off) ? buf[tid - off] : 0;
            __syncthreads();
            buf[tid] += t;
            __syncthreads();
        }
        if (i < N_NODES) {
            int ex = carry + buf[tid] - v;
            rowstart[i] = ex;
            cursor[i]   = ex;
        }
        carry += buf[255];
        __syncthreads();
    }
    if (tid == 0) rowstart[N_NODES] = carry;
}

__global__ void fill_k(const int* __restrict__ rows, const int* __restrict__ cols,
                       const float* __restrict__ vals, int* __restrict__ cursor,
                       int* __restrict__ csr_col, float* __restrict__ csr_val) {
    int e = blockIdx.x * blockDim.x + threadIdx.x;
    if (e < N_EDGES) {
        int p = atomicAdd(&cursor[rows[e]], 1);
        csr_col[p] = cols[e];
        csr_val[p] = vals[e];
    }
}

// ---------- aggregate (bf16 in/out, fp32 acc): one wave per row ----------
__device__ inline void fma8(float* acc, uint4 v, float w) {
    acc[0] += w * bflo(v.x); acc[1] += w * bfhi(v.x);
    acc[2] += w * bflo(v.y); acc[3] += w * bfhi(v.y);
    acc[4] += w * bflo(v.z); acc[5] += w * bfhi(v.z);
    acc[6] += w * bflo(v.w); acc[7] += w * bfhi(v.w);
}

__global__ __launch_bounds__(256) void agg_k(const ushort* __restrict__ s,
                                             const int* __restrict__ rowstart,
                                             const int* __restrict__ csr_col,
                                             const float* __restrict__ csr_val,
                                             const float* __restrict__ bias,
                                             ushort* __restrict__ hout) {
    const int wave = threadIdx.x >> 6, lane = threadIdx.x & 63;
    const int r = blockIdx.x * 4 + wave;
    const uint4* s4 = (const uint4*)s;
    float acc[8] = {};
    const int beg = rowstart[r], end = rowstart[r + 1];
    int j = beg;
    for (; j + 2 <= end; j += 2) {
        int   c0 = csr_col[j],   c1 = csr_col[j + 1];
        float w0 = csr_val[j],   w1 = csr_val[j + 1];
        uint4 v0 = s4[(size_t)c0 * 64 + lane];
        uint4 v1 = s4[(size_t)c1 * 64 + lane];
        fma8(acc, v0, w0);
        fma8(acc, v1, w1);
    }
    if (j < end) {
        int   c0 = csr_col[j];
        float w0 = csr_val[j];
        uint4 v0 = s4[(size_t)c0 * 64 + lane];
        fma8(acc, v0, w0);
    }
    float4 b0 = ((const float4*)bias)[lane * 2];
    float4 b1 = ((const float4*)bias)[lane * 2 + 1];
    float o[8];
    o[0] = fmaxf(acc[0] + b0.x, 0.f); o[1] = fmaxf(acc[1] + b0.y, 0.f);
    o[2] = fmaxf(acc[2] + b0.z, 0.f); o[3] = fmaxf(acc[3] + b0.w, 0.f);
    o[4] = fmaxf(acc[4] + b1.x, 0.f); o[5] = fmaxf(acc[5] + b1.y, 0.f);
    o[6] = fmaxf(acc[6] + b1.z, 0.f); o[7] = fmaxf(acc[7] + b1.w, 0.f);
    uint4 ov;
    ov.x = pack2(o[0], o[1]); ov.y = pack2(o[2], o[3]);
    ov.z = pack2(o[4], o[5]); ov.w = pack2(o[6], o[7]);
    ((uint4*)hout)[(size_t)r * 64 + lane] = ov;
}

// ---------- pool: per-channel max & sum (bf16 input) ----------
__global__ __launch_bounds__(256) void pool_k(const ushort* __restrict__ h,
                                              float* __restrict__ pmax,
                                              float* __restrict__ psum) {
    const int tid = threadIdx.x;
    const uint* h2 = (const uint*)h;
    float m0 = 0.f, m1 = 0.f, s0 = 0.f, s1 = 0.f;   // relu output >= 0
    for (int r = blockIdx.x; r < N_NODES; r += gridDim.x) {
        uint v = h2[(size_t)r * 256 + tid];
        float a = bflo(v), b = bfhi(v);
        m0 = fmaxf(m0, a); m1 = fmaxf(m1, b);
        s0 += a;           s1 += b;
    }
    atomicMax((int*)&pmax[tid * 2],     __float_as_int(m0));
    atomicMax((int*)&pmax[tid * 2 + 1], __float_as_int(m1));
    atomicAdd(&psum[tid * 2],     s0);
    atomicAdd(&psum[tid * 2 + 1], s1);
}

// ---------- head MLP + log_softmax ----------
__global__ __launch_bounds__(256) void mlp_k(const float* __restrict__ pool_max,
                                             const float* __restrict__ pool_sum,
                                             const float* __restrict__ l1W,
                                             const float* __restrict__ l1b,
                                             const float* __restrict__ l2W,
                                             const float* __restrict__ l2b,
                                             const float* __restrict__ l3W,
                                             const float* __restrict__ l3b,
                                             float* __restrict__ out) {
    __shared__ float g[1024];
    __shared__ float a1[128];
    __shared__ float a2[64];
    __shared__ float a3[10];
    const int tid = threadIdx.x;
    for (int c = tid; c < 512; c += 256) {
        g[c]       = pool_max[c] + pool_max[512 + c] + pool_max[1024 + c];
        g[512 + c] = (pool_sum[c] + pool_sum[512 + c] + pool_sum[1024 + c]) *
                     (1.0f / N_NODES);
    }
    __syncthreads();
    if (tid < 128) {
        float acc = l1b[tid];
        for (int k = 0; k < 1024; ++k) acc += g[k] * l1W[k * 128 + tid];
        a1[tid] = fmaxf(acc, 0.f);
    }
    __syncthreads();
    if (tid < 64) {
        float acc = l2b[tid];
        for (int k = 0; k < 128; ++k) acc += a1[k] * l2W[k * 64 + tid];
        a2[tid] = fmaxf(acc, 0.f);
    }
    __syncthreads();
    if (tid < 10) {
        float acc = l3b[tid];
        for (int k = 0; k < 64; ++k) acc += a2[k] * l3W[k * 10 + tid];
        a3[tid] = acc;
    }
    __syncthreads();
    if (tid == 0) {
        float m = a3[0];
        for (int j = 1; j < 10; ++j) m = fmaxf(m, a3[j]);
        float ssum = 0.f;
        for (int j = 0; j < 10; ++j) ssum += expf(a3[j] - m);
        float lse = m + logf(ssum);
        for (int j = 0; j < 10; ++j) out[j] = a3[j] - lse;
    }
}

extern "C" void kernel_launch(void* const* d_in, const int* in_sizes, int n_in,
                              void* d_out, int out_size, void* d_ws, size_t ws_size,
                              hipStream_t stream) {
    const float* x    = (const float*)d_in[0];
    const int*   rows = (const int*)  d_in[1];
    const int*   cols = (const int*)  d_in[2];
    const float* vals = (const float*)d_in[3];
    const float* W1   = (const float*)d_in[4];
    const float* b1   = (const float*)d_in[5];
    const float* W2   = (const float*)d_in[6];
    const float* b2   = (const float*)d_in[7];
    const float* W3   = (const float*)d_in[8];
    const float* b3   = (const float*)d_in[9];
    const float* l1W  = (const float*)d_in[10];
    const float* l1b  = (const float*)d_in[11];
    const float* l2W  = (const float*)d_in[12];
    const float* l2b  = (const float*)d_in[13];
    const float* l3W  = (const float*)d_in[14];
    const float* l3b  = (const float*)d_in[15];
    float* out = (float*)d_out;

    char* ws = (char*)d_ws;
    size_t off = 0;
    auto alloc = [&](size_t bytes) {
        void* p = ws + off;
        off += (bytes + 255) & ~(size_t)255;
        return p;
    };
    ushort* xb       = (ushort*)alloc((size_t)N_NODES * HD * 2);  // 20.5 MB
    ushort* s        = (ushort*)alloc((size_t)N_NODES * HD * 2);  // 20.5 MB
    ushort* hb       = (ushort*)alloc((size_t)N_NODES * HD * 2);  // 20.5 MB
    ushort* wt1      = (ushort*)alloc((size_t)HD * HD * 2);
    ushort* wt2      = (ushort*)alloc((size_t)HD * HD * 2);
    ushort* wt3      = (ushort*)alloc((size_t)HD * HD * 2);
    int*    deg      = (int*)   alloc((size_t)N_NODES * 4);
    int*    rowstart = (int*)   alloc((size_t)(N_NODES + 1) * 4);
    int*    cursor   = (int*)   alloc((size_t)N_NODES * 4);
    int*    csr_col  = (int*)   alloc((size_t)N_EDGES * 4);
    float*  csr_val  = (float*) alloc((size_t)N_EDGES * 4);
    float*  pmax     = (float*) alloc((size_t)3 * 512 * 4);
    float*  psum     = (float*) alloc((size_t)3 * 512 * 4);
    (void)ws_size; (void)in_sizes; (void)n_in; (void)out_size;

    hipMemsetAsync(deg,  0, (size_t)N_NODES * 4, stream);
    hipMemsetAsync(pmax, 0, (size_t)3 * 512 * 4, stream);
    hipMemsetAsync(psum, 0, (size_t)3 * 512 * 4, stream);

    // prep: x -> bf16, W -> bf16 transposed, CSR build
    cvt_k<<<(N_NODES * HD / 8 + 255) / 256, 256, 0, stream>>>(x, xb, N_NODES * HD / 8);
    wt_k<<<dim3(8, 8, 3), 256, 0, stream>>>(W1, W2, W3, wt1, wt2, wt3);
    const int EB = (N_EDGES + 255) / 256;
    hist_k<<<EB, 256, 0, stream>>>(rows, deg);
    scan_k<<<1, 256, 0, stream>>>(deg, rowstart, cursor);
    fill_k<<<EB, 256, 0, stream>>>(rows, cols, vals, cursor, csr_col, csr_val);

    dim3 ggrid(HD / 128, (N_NODES + 127) / 128);

    // layer 1
    gemm_bf16_k<<<ggrid, 256, 0, stream>>>(xb, wt1, s, N_NODES);
    agg_k<<<N_NODES / 4, 256, 0, stream>>>(s, rowstart, csr_col, csr_val, b1, hb);
    pool_k<<<256, 256, 0, stream>>>(hb, pmax, psum);

    // layer 2
    gemm_bf16_k<<<ggrid, 256, 0, stream>>>(hb, wt2, s, N_NODES);
    agg_k<<<N_NODES / 4, 256, 0, stream>>>(s, rowstart, csr_col, csr_val, b2, hb);
    pool_k<<<256, 256, 0, stream>>>(hb, pmax + 512, psum + 512);

    // layer 3
    gemm_bf16_k<<<ggrid, 256, 0, stream>>>(hb, wt3, s, N_NODES);
    agg_k<<<N_NODES / 4, 256, 0, stream>>>(s, rowstart, csr_col, csr_val, b3, hb);
    pool_k<<<256, 256, 0, stream>>>(hb, pmax + 1024, psum + 1024);

    mlp_k<<<1, 256, 0, stream>>>(pmax, psum, l1W, l1b, l2W, l2b, l3W, l3b, out);
}

// Round 3
// 489.157 us; speedup vs baseline: 2.3235x; 1.1554x over previous
//
#include <hip/hip_runtime.h>
#include <hip/hip_bf16.h>

#define N_NODES 20000
#define N_EDGES 320000
#define HD 512

typedef __attribute__((ext_vector_type(8))) short bf16x8;
typedef __attribute__((ext_vector_type(4))) float f32x4;

// ---------- bf16 helpers (RNE pack, cheap unpack) ----------
__device__ inline ushort f2bf(float f) {
    uint u = __float_as_uint(f);
    uint r = (u + 0x7fffu + ((u >> 16) & 1u)) >> 16;
    return (ushort)r;
}
__device__ inline uint pack2(float a, float b) {
    return (uint)f2bf(a) | ((uint)f2bf(b) << 16);
}
__device__ inline float bflo(uint u) { return __uint_as_float(u << 16); }
__device__ inline float bfhi(uint u) { return __uint_as_float(u & 0xffff0000u); }

// ---------- convert fp32 -> bf16, 8 elems/thread ----------
__global__ __launch_bounds__(256) void cvt_k(const float* __restrict__ in,
                                             ushort* __restrict__ out, int nchunk) {
    int c = blockIdx.x * 256 + threadIdx.x;
    if (c < nchunk) {
        const float4* p = (const float4*)in + (size_t)c * 2;
        float4 a = p[0], b = p[1];
        uint4 o;
        o.x = pack2(a.x, a.y); o.y = pack2(a.z, a.w);
        o.z = pack2(b.x, b.y); o.w = pack2(b.z, b.w);
        ((uint4*)out)[c] = o;
    }
}

// ---------- W [K][N] fp32 -> Wt [N][K] bf16 (LDS tile transpose) ----------
__global__ __launch_bounds__(256) void wt_k(const float* __restrict__ W0,
                                            const float* __restrict__ W1,
                                            const float* __restrict__ W2,
                                            ushort* __restrict__ T0,
                                            ushort* __restrict__ T1,
                                            ushort* __restrict__ T2) {
    const float* W = (blockIdx.z == 0) ? W0 : (blockIdx.z == 1) ? W1 : W2;
    ushort* T      = (blockIdx.z == 0) ? T0 : (blockIdx.z == 1) ? T1 : T2;
    __shared__ float t[64][65];
    int c = threadIdx.x & 63, r4 = threadIdx.x >> 6;
    int kb = blockIdx.x * 64, nb = blockIdx.y * 64;
    #pragma unroll
    for (int l = 0; l < 16; ++l) {
        int r = l * 4 + r4;
        t[r][c] = W[(size_t)(kb + r) * HD + nb + c];
    }
    __syncthreads();
    #pragma unroll
    for (int l = 0; l < 16; ++l) {
        int r = l * 4 + r4;
        T[(size_t)(nb + r) * HD + kb + c] = f2bf(t[c][r]);
    }
}

// ---------- bf16 MFMA GEMM: C[M,512] = A[M,512] * Bt[n][k]^T ----------
#define LDSK 40   // 32 + 8 pad: frag ds_read_b128 -> 2-way bank alias = free
__global__ __launch_bounds__(256) void gemm_bf16_k(const ushort* __restrict__ A,
                                                   const ushort* __restrict__ Bt,
                                                   ushort* __restrict__ C, int M) {
    __shared__ __align__(16) short As[128 * LDSK];
    __shared__ __align__(16) short Bs[128 * LDSK];
    const int tid = threadIdx.x;
    const int lane = tid & 63;
    const int wave = tid >> 6;
    const int l15 = lane & 15;
    const int q = lane >> 4;
    const int wrow = wave >> 1, wcol = wave & 1;
    const int row0 = blockIdx.y * 128;
    const int col0 = blockIdx.x * 128;

    f32x4 acc[4][4] = {};

    for (int k0 = 0; k0 < HD; k0 += 32) {
        #pragma unroll
        for (int l = 0; l < 2; ++l) {
            int c = tid + l * 256;          // 512 chunks of 8 bf16
            int row = c >> 2, kc = c & 3;
            uint4 v = make_uint4(0u, 0u, 0u, 0u);
            int gr = row0 + row;
            if (gr < M) v = *(const uint4*)&A[(size_t)gr * HD + k0 + kc * 8];
            *(uint4*)&As[row * LDSK + kc * 8] = v;
            uint4 w = *(const uint4*)&Bt[(size_t)(col0 + row) * HD + k0 + kc * 8];
            *(uint4*)&Bs[row * LDSK + kc * 8] = w;
        }
        __syncthreads();
        bf16x8 aF[4], bF[4];
        #pragma unroll
        for (int i = 0; i < 4; ++i)
            aF[i] = *(bf16x8*)&As[(wrow * 64 + i * 16 + l15) * LDSK + q * 8];
        #pragma unroll
        for (int j = 0; j < 4; ++j)
            bF[j] = *(bf16x8*)&Bs[(wcol * 64 + j * 16 + l15) * LDSK + q * 8];
        #pragma unroll
        for (int i = 0; i < 4; ++i)
            #pragma unroll
            for (int j = 0; j < 4; ++j)
                acc[i][j] = __builtin_amdgcn_mfma_f32_16x16x32_bf16(aF[i], bF[j], acc[i][j], 0, 0, 0);
        __syncthreads();
    }
    #pragma unroll
    for (int i = 0; i < 4; ++i) {
        #pragma unroll
        for (int r = 0; r < 4; ++r) {
            int gr = row0 + wrow * 64 + i * 16 + q * 4 + r;
            if (gr < M) {
                #pragma unroll
                for (int j = 0; j < 4; ++j) {
                    int gc = col0 + wcol * 64 + j * 16 + l15;
                    C[(size_t)gr * HD + gc] = f2bf(acc[i][j][r]);
                }
            }
        }
    }
}

// ---------- CSR build ----------
__global__ void hist_k(const int* __restrict__ rows, int* __restrict__ deg) {
    int e = blockIdx.x * blockDim.x + threadIdx.x;
    if (e < N_EDGES) atomicAdd(&deg[rows[e]], 1);
}

// one workgroup, 16 waves, shuffle-scan: ~40 barriers total
__global__ __launch_bounds__(1024) void scan_k(const int* __restrict__ deg,
                                               int* __restrict__ rowstart,
                                               int* __restrict__ cursor) {
    __shared__ int wsum[16];
    const int tid = threadIdx.x;
    const int lane = tid & 63, wv = tid >> 6;
    int carry = 0;
    for (int base = 0; base < N_NODES; base += 1024) {
        int i = base + tid;
        int v = (i < N_NODES) ? deg[i] : 0;
        int incl = v;
        #pragma unroll
        for (int off = 1; off < 64; off <<= 1) {
            int t = __shfl_up(incl, off, 64);
            if (lane >= off) incl += t;
        }
        if (lane == 63) wsum[wv] = incl;
        __syncthreads();
        int woff = 0, tot = 0;
        #pragma unroll
        for (int w = 0; w < 16; ++w) {
            int sv = wsum[w];
            if (w < wv) woff += sv;
            tot += sv;
        }
        if (i < N_NODES) {
            int ex = carry + woff + incl - v;
            rowstart[i] = ex;
            cursor[i]   = ex;
        }
        carry += tot;
        __syncthreads();
    }
    if (tid == 0) rowstart[N_NODES] = carry;
}

__global__ void fill_k(const int* __restrict__ rows, const int* __restrict__ cols,
                       const float* __restrict__ vals, int* __restrict__ cursor,
                       int* __restrict__ csr_col, float* __restrict__ csr_val) {
    int e = blockIdx.x * blockDim.x + threadIdx.x;
    if (e < N_EDGES) {
        int p = atomicAdd(&cursor[rows[e]], 1);
        csr_col[p] = cols[e];
        csr_val[p] = vals[e];
    }
}

// ---------- aggregate (bf16 in/out, fp32 acc): one wave per row ----------
__device__ inline void fma8(float* acc, uint4 v, float w) {
    acc[0] += w * bflo(v.x); acc[1] += w * bfhi(v.x);
    acc[2] += w * bflo(v.y); acc[3] += w * bfhi(v.y);
    acc[4] += w * bflo(v.z); acc[5] += w * bfhi(v.z);
    acc[6] += w * bflo(v.w); acc[7] += w * bfhi(v.w);
}

__global__ __launch_bounds__(256) void agg_k(const ushort* __restrict__ s,
                                             const int* __restrict__ rowstart,
                                             const int* __restrict__ csr_col,
                                             const float* __restrict__ csr_val,
                                             const float* __restrict__ bias,
                                             ushort* __restrict__ hout) {
    const int wave = threadIdx.x >> 6, lane = threadIdx.x & 63;
    const int r = blockIdx.x * 4 + wave;
    const uint4* s4 = (const uint4*)s;
    float acc[8] = {};
    const int beg = rowstart[r], end = rowstart[r + 1];
    int j = beg;
    for (; j + 4 <= end; j += 4) {
        int   c0 = csr_col[j],     c1 = csr_col[j + 1];
        int   c2 = csr_col[j + 2], c3 = csr_col[j + 3];
        float w0 = csr_val[j],     w1 = csr_val[j + 1];
        float w2 = csr_val[j + 2], w3 = csr_val[j + 3];
        uint4 v0 = s4[(size_t)c0 * 64 + lane];
        uint4 v1 = s4[(size_t)c1 * 64 + lane];
        uint4 v2 = s4[(size_t)c2 * 64 + lane];
        uint4 v3 = s4[(size_t)c3 * 64 + lane];
        fma8(acc, v0, w0);
        fma8(acc, v1, w1);
        fma8(acc, v2, w2);
        fma8(acc, v3, w3);
    }
    for (; j < end; ++j) {
        int   c0 = csr_col[j];
        float w0 = csr_val[j];
        uint4 v0 = s4[(size_t)c0 * 64 + lane];
        fma8(acc, v0, w0);
    }
    float4 b0 = ((const float4*)bias)[lane * 2];
    float4 b1 = ((const float4*)bias)[lane * 2 + 1];
    float o[8];
    o[0] = fmaxf(acc[0] + b0.x, 0.f); o[1] = fmaxf(acc[1] + b0.y, 0.f);
    o[2] = fmaxf(acc[2] + b0.z, 0.f); o[3] = fmaxf(acc[3] + b0.w, 0.f);
    o[4] = fmaxf(acc[4] + b1.x, 0.f); o[5] = fmaxf(acc[5] + b1.y, 0.f);
    o[6] = fmaxf(acc[6] + b1.z, 0.f); o[7] = fmaxf(acc[7] + b1.w, 0.f);
    uint4 ov;
    ov.x = pack2(o[0], o[1]); ov.y = pack2(o[2], o[3]);
    ov.z = pack2(o[4], o[5]); ov.w = pack2(o[6], o[7]);
    ((uint4*)hout)[(size_t)r * 64 + lane] = ov;
}

// ---------- pool: per-channel max & sum (bf16 input) ----------
__global__ __launch_bounds__(256) void pool_k(const ushort* __restrict__ h,
                                              float* __restrict__ pmax,
                                              float* __restrict__ psum) {
    const int tid = threadIdx.x;
    const uint* h2 = (const uint*)h;
    float m0 = 0.f, m1 = 0.f, s0 = 0.f, s1 = 0.f;   // relu output >= 0
    for (int r = blockIdx.x; r < N_NODES; r += gridDim.x) {
        uint v = h2[(size_t)r * 256 + tid];
        float a = bflo(v), b = bfhi(v);
        m0 = fmaxf(m0, a); m1 = fmaxf(m1, b);
        s0 += a;           s1 += b;
    }
    atomicMax((int*)&pmax[tid * 2],     __float_as_int(m0));
    atomicMax((int*)&pmax[tid * 2 + 1], __float_as_int(m1));
    atomicAdd(&psum[tid * 2],     s0);
    atomicAdd(&psum[tid * 2 + 1], s1);
}

// ---------- head MLP + log_softmax ----------
__global__ __launch_bounds__(256) void mlp_k(const float* __restrict__ pool_max,
                                             const float* __restrict__ pool_sum,
                                             const float* __restrict__ l1W,
                                             const float* __restrict__ l1b,
                                             const float* __restrict__ l2W,
                                             const float* __restrict__ l2b,
                                             const float* __restrict__ l3W,
                                             const float* __restrict__ l3b,
                                             float* __restrict__ out) {
    __shared__ float g[1024];
    __shared__ float a1[128];
    __shared__ float a2[64];
    __shared__ float a3[10];
    const int tid = threadIdx.x;
    for (int c = tid; c < 512; c += 256) {
        g[c]       = pool_max[c] + pool_max[512 + c] + pool_max[1024 + c];
        g[512 + c] = (pool_sum[c] + pool_sum[512 + c] + pool_sum[1024 + c]) *
                     (1.0f / N_NODES);
    }
    __syncthreads();
    if (tid < 128) {
        float acc = l1b[tid];
        for (int k = 0; k < 1024; ++k) acc += g[k] * l1W[k * 128 + tid];
        a1[tid] = fmaxf(acc, 0.f);
    }
    __syncthreads();
    if (tid < 64) {
        float acc = l2b[tid];
        for (int k = 0; k < 128; ++k) acc += a1[k] * l2W[k * 64 + tid];
        a2[tid] = fmaxf(acc, 0.f);
    }
    __syncthreads();
    if (tid < 10) {
        float acc = l3b[tid];
        for (int k = 0; k < 64; ++k) acc += a2[k] * l3W[k * 10 + tid];
        a3[tid] = acc;
    }
    __syncthreads();
    if (tid == 0) {
        float m = a3[0];
        for (int j = 1; j < 10; ++j) m = fmaxf(m, a3[j]);
        float ssum = 0.f;
        for (int j = 0; j < 10; ++j) ssum += expf(a3[j] - m);
        float lse = m + logf(ssum);
        for (int j = 0; j < 10; ++j) out[j] = a3[j] - lse;
    }
}

extern "C" void kernel_launch(void* const* d_in, const int* in_sizes, int n_in,
                              void* d_out, int out_size, void* d_ws, size_t ws_size,
                              hipStream_t stream) {
    const float* x    = (const float*)d_in[0];
    const int*   rows = (const int*)  d_in[1];
    const int*   cols = (const int*)  d_in[2];
    const float* vals = (const float*)d_in[3];
    const float* W1   = (const float*)d_in[4];
    const float* b1   = (const float*)d_in[5];
    const float* W2   = (const float*)d_in[6];
    const float* b2   = (const float*)d_in[7];
    const float* W3   = (const float*)d_in[8];
    const float* b3   = (const float*)d_in[9];
    const float* l1W  = (const float*)d_in[10];
    const float* l1b  = (const float*)d_in[11];
    const float* l2W  = (const float*)d_in[12];
    const float* l2b  = (const float*)d_in[13];
    const float* l3W  = (const float*)d_in[14];
    const float* l3b  = (const float*)d_in[15];
    float* out = (float*)d_out;

    char* ws = (char*)d_ws;
    size_t off = 0;
    auto alloc = [&](size_t bytes) {
        void* p = ws + off;
        off += (bytes + 255) & ~(size_t)255;
        return p;
    };
    ushort* xb       = (ushort*)alloc((size_t)N_NODES * HD * 2);  // 20.5 MB
    ushort* s        = (ushort*)alloc((size_t)N_NODES * HD * 2);  // 20.5 MB
    ushort* hb       = (ushort*)alloc((size_t)N_NODES * HD * 2);  // 20.5 MB
    ushort* wt1      = (ushort*)alloc((size_t)HD * HD * 2);
    ushort* wt2      = (ushort*)alloc((size_t)HD * HD * 2);
    ushort* wt3      = (ushort*)alloc((size_t)HD * HD * 2);
    // --- zero-init span: deg + pmax + psum contiguous, one memset ---
    size_t zbase = off;
    int*    deg      = (int*)   alloc((size_t)N_NODES * 4);
    float*  pmax     = (float*) alloc((size_t)3 * 512 * 4);
    float*  psum     = (float*) alloc((size_t)3 * 512 * 4);
    size_t zlen = off - zbase;
    int*    rowstart = (int*)   alloc((size_t)(N_NODES + 1) * 4);
    int*    cursor   = (int*)   alloc((size_t)N_NODES * 4);
    int*    csr_col  = (int*)   alloc((size_t)N_EDGES * 4);
    float*  csr_val  = (float*) alloc((size_t)N_EDGES * 4);
    (void)ws_size; (void)in_sizes; (void)n_in; (void)out_size;

    hipMemsetAsync(ws + zbase, 0, zlen, stream);

    // prep: x -> bf16, W -> bf16 transposed, CSR build
    cvt_k<<<(N_NODES * HD / 8 + 255) / 256, 256, 0, stream>>>(x, xb, N_NODES * HD / 8);
    wt_k<<<dim3(8, 8, 3), 256, 0, stream>>>(W1, W2, W3, wt1, wt2, wt3);
    const int EB = (N_EDGES + 255) / 256;
    hist_k<<<EB, 256, 0, stream>>>(rows, deg);
    scan_k<<<1, 1024, 0, stream>>>(deg, rowstart, cursor);
    fill_k<<<EB, 256, 0, stream>>>(rows, cols, vals, cursor, csr_col, csr_val);

    dim3 ggrid(HD / 128, (N_NODES + 127) / 128);

    // layer 1
    gemm_bf16_k<<<ggrid, 256, 0, stream>>>(xb, wt1, s, N_NODES);
    agg_k<<<N_NODES / 4, 256, 0, stream>>>(s, rowstart, csr_col, csr_val, b1, hb);
    pool_k<<<256, 256, 0, stream>>>(hb, pmax, psum);

    // layer 2
    gemm_bf16_k<<<ggrid, 256, 0, stream>>>(hb, wt2, s, N_NODES);
    agg_k<<<N_NODES / 4, 256, 0, stream>>>(s, rowstart, csr_col, csr_val, b2, hb);
    pool_k<<<256, 256, 0, stream>>>(hb, pmax + 512, psum + 512);

    // layer 3
    gemm_bf16_k<<<ggrid, 256, 0, stream>>>(hb, wt3, s, N_NODES);
    agg_k<<<N_NODES / 4, 256, 0, stream>>>(s, rowstart, csr_col, csr_val, b3, hb);
    pool_k<<<256, 256, 0, stream>>>(hb, pmax + 1024, psum + 1024);

    mlp_k<<<1, 256, 0, stream>>>(pmax, psum, l1W, l1b, l2W, l2b, l3W, l3b, out);
}